// Round 1
// baseline (1920.373 us; speedup 1.0000x reference)
//
#include <hip/hip_runtime.h>
#include <hip/hip_bf16.h>
#include <math.h>

constexpr int Lq   = 2048;   // tokens (N_CLS * K_SHOT)
constexpr int DMOD = 2048;   // d_model
constexpr int NH   = 16;     // heads
constexpr int DK_  = 128;    // d_k == d_v

// ---------------- GEMM TN : C = scale * (A @ W^T) (+ bias + residual) ----
// A: [M x Kd] row-major (lda), W: [N x Kd] row-major (ldw), C: [M x N] (ldc)
// Tiles: BM=128, BN=64, BK=16. 256 threads. Each thread: 8x4 outputs.
__global__ __launch_bounds__(256)
void gemm_tn(const float* __restrict__ A, const float* __restrict__ W,
             float* __restrict__ C,
             int Kd, int lda, int ldw, int ldc,
             long long zA, long long zW, long long zC,
             float scale,
             const float* __restrict__ bias,
             const float* __restrict__ residual, int ldr)
{
  A += zA * blockIdx.z;
  W += zW * blockIdx.z;
  C += zC * blockIdx.z;

  __shared__ float As[16][128];
  __shared__ float Ws[16][64];

  const int tid = threadIdx.x;
  const int tx = tid & 15;        // 0..15 -> 4-col group
  const int ty = tid >> 4;        // 0..15 -> 8-row group
  const int m0 = blockIdx.y * 128;
  const int n0 = blockIdx.x * 64;

  const int lr = tid >> 2;        // 0..63
  const int lc = (tid & 3) << 2;  // 0,4,8,12

  float acc[8][4];
  #pragma unroll
  for (int i = 0; i < 8; ++i)
    #pragma unroll
    for (int j = 0; j < 4; ++j) acc[i][j] = 0.f;

  for (int kt = 0; kt < Kd; kt += 16) {
    const float4 a0 = *(const float4*)&A[(long long)(m0 + lr)      * lda + kt + lc];
    const float4 a1 = *(const float4*)&A[(long long)(m0 + lr + 64) * lda + kt + lc];
    const float4 w0 = *(const float4*)&W[(long long)(n0 + lr)      * ldw + kt + lc];
    __syncthreads();
    As[lc+0][lr]    = a0.x; As[lc+1][lr]    = a0.y; As[lc+2][lr]    = a0.z; As[lc+3][lr]    = a0.w;
    As[lc+0][lr+64] = a1.x; As[lc+1][lr+64] = a1.y; As[lc+2][lr+64] = a1.z; As[lc+3][lr+64] = a1.w;
    Ws[lc+0][lr]    = w0.x; Ws[lc+1][lr]    = w0.y; Ws[lc+2][lr]    = w0.z; Ws[lc+3][lr]    = w0.w;
    __syncthreads();
    #pragma unroll
    for (int k = 0; k < 16; ++k) {
      const float4 av0 = *(const float4*)&As[k][ty * 8];
      const float4 av1 = *(const float4*)&As[k][ty * 8 + 4];
      const float4 bv  = *(const float4*)&Ws[k][tx * 4];
      const float a[8] = {av0.x, av0.y, av0.z, av0.w, av1.x, av1.y, av1.z, av1.w};
      const float b[4] = {bv.x, bv.y, bv.z, bv.w};
      #pragma unroll
      for (int i = 0; i < 8; ++i)
        #pragma unroll
        for (int j = 0; j < 4; ++j)
          acc[i][j] = fmaf(a[i], b[j], acc[i][j]);
    }
  }

  #pragma unroll
  for (int i = 0; i < 8; ++i) {
    const int m = m0 + ty * 8 + i;
    const int n = n0 + tx * 4;
    float4 r;
    r.x = acc[i][0] * scale; r.y = acc[i][1] * scale;
    r.z = acc[i][2] * scale; r.w = acc[i][3] * scale;
    if (bias) { r.x += bias[n]; r.y += bias[n+1]; r.z += bias[n+2]; r.w += bias[n+3]; }
    if (residual) {
      const float4 rv = *(const float4*)&residual[(long long)m * ldr + n];
      r.x += rv.x; r.y += rv.y; r.z += rv.z; r.w += rv.w;
    }
    *(float4*)&C[(long long)m * ldc + n] = r;
  }
}

// ---------------- GEMM NN : C = A @ B ----
// A: [M x Kd] row-major (lda), B: [Kd x N] row-major (ldb), C: [M x N] (ldc)
// Tiles: BM=128, BN=64, BK=16.
__global__ __launch_bounds__(256)
void gemm_nn(const float* __restrict__ A, const float* __restrict__ B,
             float* __restrict__ C,
             int Kd, int lda, int ldb, int ldc,
             long long zA, long long zB, long long zC)
{
  A += zA * blockIdx.z;
  B += zB * blockIdx.z;
  C += zC * blockIdx.z;

  __shared__ float As[16][128];
  __shared__ float Bs[16][64];

  const int tid = threadIdx.x;
  const int tx = tid & 15;
  const int ty = tid >> 4;
  const int m0 = blockIdx.y * 128;
  const int n0 = blockIdx.x * 64;

  const int lr = tid >> 2;        // 0..63
  const int lc = (tid & 3) << 2;  // 0,4,8,12
  const int br = tid >> 4;        // 0..15
  const int bc = (tid & 15) << 2; // 0..60

  float acc[8][4];
  #pragma unroll
  for (int i = 0; i < 8; ++i)
    #pragma unroll
    for (int j = 0; j < 4; ++j) acc[i][j] = 0.f;

  for (int kt = 0; kt < Kd; kt += 16) {
    const float4 a0 = *(const float4*)&A[(long long)(m0 + lr)      * lda + kt + lc];
    const float4 a1 = *(const float4*)&A[(long long)(m0 + lr + 64) * lda + kt + lc];
    const float4 b0 = *(const float4*)&B[(long long)(kt + br) * ldb + n0 + bc];
    __syncthreads();
    As[lc+0][lr]    = a0.x; As[lc+1][lr]    = a0.y; As[lc+2][lr]    = a0.z; As[lc+3][lr]    = a0.w;
    As[lc+0][lr+64] = a1.x; As[lc+1][lr+64] = a1.y; As[lc+2][lr+64] = a1.z; As[lc+3][lr+64] = a1.w;
    *(float4*)&Bs[br][bc] = b0;
    __syncthreads();
    #pragma unroll
    for (int k = 0; k < 16; ++k) {
      const float4 av0 = *(const float4*)&As[k][ty * 8];
      const float4 av1 = *(const float4*)&As[k][ty * 8 + 4];
      const float4 bv  = *(const float4*)&Bs[k][tx * 4];
      const float a[8] = {av0.x, av0.y, av0.z, av0.w, av1.x, av1.y, av1.z, av1.w};
      const float b[4] = {bv.x, bv.y, bv.z, bv.w};
      #pragma unroll
      for (int i = 0; i < 8; ++i)
        #pragma unroll
        for (int j = 0; j < 4; ++j)
          acc[i][j] = fmaf(a[i], b[j], acc[i][j]);
    }
  }

  #pragma unroll
  for (int i = 0; i < 8; ++i) {
    const int m = m0 + ty * 8 + i;
    const int n = n0 + tx * 4;
    float4 r;
    r.x = acc[i][0]; r.y = acc[i][1]; r.z = acc[i][2]; r.w = acc[i][3];
    *(float4*)&C[(long long)m * ldc + n] = r;
  }
}

// ---------------- Softmax over last axis + episodic class-weight mask ----
// One block per row (h, i). 256 threads x 8 elements = 2048 cols.
__global__ __launch_bounds__(256)
void softmax_mask(float* __restrict__ attn,
                  const float* __restrict__ aw,
                  const int* __restrict__ Kp)
{
  __shared__ float red[4];
  const int row = blockIdx.x;            // h*Lq + i
  const int i = row & (Lq - 1);
  float* p = attn + (long long)row * Lq;
  const int t = threadIdx.x;

  float x[8];
  float4 v0 = *(const float4*)&p[t * 8];
  float4 v1 = *(const float4*)&p[t * 8 + 4];
  x[0]=v0.x; x[1]=v0.y; x[2]=v0.z; x[3]=v0.w;
  x[4]=v1.x; x[5]=v1.y; x[6]=v1.z; x[7]=v1.w;

  float m = x[0];
  #pragma unroll
  for (int e = 1; e < 8; ++e) m = fmaxf(m, x[e]);
  #pragma unroll
  for (int off = 32; off > 0; off >>= 1) m = fmaxf(m, __shfl_down(m, off));
  const int lane = t & 63, wid = t >> 6;
  if (lane == 0) red[wid] = m;
  __syncthreads();
  m = fmaxf(fmaxf(red[0], red[1]), fmaxf(red[2], red[3]));
  __syncthreads();

  float s = 0.f;
  #pragma unroll
  for (int e = 0; e < 8; ++e) { x[e] = __expf(x[e] - m); s += x[e]; }
  #pragma unroll
  for (int off = 32; off > 0; off >>= 1) s += __shfl_down(s, off);
  if (lane == 0) red[wid] = s;
  __syncthreads();
  s = red[0] + red[1] + red[2] + red[3];
  const float inv = 1.f / s;

  const float wss = tanhf(aw[0]);
  const float wsc = tanhf(aw[1]);
  const float wdc = tanhf(aw[2]);
  const int Kv = *Kp;
  const int ci = i / Kv;

  #pragma unroll
  for (int e = 0; e < 8; ++e) {
    const int j = t * 8 + e;
    const float w = (j == i) ? wss : ((j / Kv == ci) ? wsc : wdc);
    x[e] *= inv * w;
  }
  v0.x=x[0]; v0.y=x[1]; v0.z=x[2]; v0.w=x[3];
  v1.x=x[4]; v1.y=x[5]; v1.z=x[6]; v1.w=x[7];
  *(float4*)&p[t * 8]     = v0;
  *(float4*)&p[t * 8 + 4] = v1;
}

// ---------------- Rowwise LayerNorm ----
__global__ __launch_bounds__(256)
void layernorm_k(const float* __restrict__ X,
                 const float* __restrict__ gg, const float* __restrict__ bb,
                 float* __restrict__ O)
{
  __shared__ float redA[4], redB[4];
  const int row = blockIdx.x;
  const int t = threadIdx.x;
  const float* p = X + (long long)row * DMOD;

  float x[8];
  float4 v0 = *(const float4*)&p[t * 8];
  float4 v1 = *(const float4*)&p[t * 8 + 4];
  x[0]=v0.x; x[1]=v0.y; x[2]=v0.z; x[3]=v0.w;
  x[4]=v1.x; x[5]=v1.y; x[6]=v1.z; x[7]=v1.w;

  float s = 0.f, s2 = 0.f;
  #pragma unroll
  for (int e = 0; e < 8; ++e) { s += x[e]; s2 += x[e] * x[e]; }
  #pragma unroll
  for (int off = 32; off > 0; off >>= 1) {
    s  += __shfl_down(s, off);
    s2 += __shfl_down(s2, off);
  }
  const int lane = t & 63, wid = t >> 6;
  if (lane == 0) { redA[wid] = s; redB[wid] = s2; }
  __syncthreads();
  s  = redA[0] + redA[1] + redA[2] + redA[3];
  s2 = redB[0] + redB[1] + redB[2] + redB[3];

  const float mu  = s * (1.f / (float)DMOD);
  const float var = s2 * (1.f / (float)DMOD) - mu * mu;
  const float rs  = rsqrtf(var + 1e-5f);

  float y[8];
  #pragma unroll
  for (int e = 0; e < 8; ++e) {
    const int j = t * 8 + e;
    y[e] = (x[e] - mu) * rs * gg[j] + bb[j];
  }
  v0.x=y[0]; v0.y=y[1]; v0.z=y[2]; v0.w=y[3];
  v1.x=y[4]; v1.y=y[5]; v1.z=y[6]; v1.w=y[7];
  float* o = O + (long long)row * DMOD;
  *(float4*)&o[t * 8]     = v0;
  *(float4*)&o[t * 8 + 4] = v1;
}

extern "C" void kernel_launch(void* const* d_in, const int* in_sizes, int n_in,
                              void* d_out, int out_size, void* d_ws, size_t ws_size,
                              hipStream_t stream)
{
  const float* q    = (const float*)d_in[0];
  const float* k    = (const float*)d_in[1];
  const float* v    = (const float*)d_in[2];
  const float* w_qs = (const float*)d_in[3];
  const float* w_ks = (const float*)d_in[4];
  const float* w_vs = (const float*)d_in[5];
  const float* aw   = (const float*)d_in[6];
  const float* fc_w = (const float*)d_in[7];
  const float* fc_b = (const float*)d_in[8];
  const float* ln_g = (const float*)d_in[9];
  const float* ln_b = (const float*)d_in[10];
  const int*   Kp   = (const int*)d_in[12];

  float* out  = (float*)d_out;                       // [Lq, DMOD]
  float* attn = out + (size_t)Lq * DMOD;             // [NH, Lq, Lq]

  float* qh  = (float*)d_ws;                         // [Lq, 2048]
  float* kh  = qh + (size_t)Lq * DMOD;
  float* vh  = kh + (size_t)Lq * DMOD;
  float* oc  = vh + (size_t)Lq * DMOD;               // attn output, concat heads
  float* pre = qh;                                   // reuse: pre-LN buffer

  const dim3 blk(256);
  const float qk_scale = 1.0f / sqrtf((float)DK_);

  // QKV projections: [2048,2048] = X @ W^T
  gemm_tn<<<dim3(32, 16, 1), blk, 0, stream>>>(q, w_qs, qh, DMOD, DMOD, DMOD, DMOD,
                                               0, 0, 0, 1.f, nullptr, nullptr, 0);
  gemm_tn<<<dim3(32, 16, 1), blk, 0, stream>>>(k, w_ks, kh, DMOD, DMOD, DMOD, DMOD,
                                               0, 0, 0, 1.f, nullptr, nullptr, 0);
  gemm_tn<<<dim3(32, 16, 1), blk, 0, stream>>>(v, w_vs, vh, DMOD, DMOD, DMOD, DMOD,
                                               0, 0, 0, 1.f, nullptr, nullptr, 0);

  // S_h = qh_h @ kh_h^T / sqrt(dk)  (batched over heads via z, column offsets)
  gemm_tn<<<dim3(32, 16, NH), blk, 0, stream>>>(qh, kh, attn, DK_, DMOD, DMOD, Lq,
                                                128, 128, (long long)Lq * Lq,
                                                qk_scale, nullptr, nullptr, 0);

  // softmax + episodic mask (writes the attn OUTPUT in place)
  softmax_mask<<<dim3(NH * Lq), blk, 0, stream>>>(attn, aw, Kp);

  // O_h = attn_h @ vh_h  -> concat into oc[:, h*128:(h+1)*128]
  gemm_nn<<<dim3(2, 16, NH), blk, 0, stream>>>(attn, vh, oc, Lq, Lq, DMOD, DMOD,
                                               (long long)Lq * Lq, 128, 128);

  // FC + bias + residual
  gemm_tn<<<dim3(32, 16, 1), blk, 0, stream>>>(oc, fc_w, pre, DMOD, DMOD, DMOD, DMOD,
                                               0, 0, 0, 1.f, fc_b, q, DMOD);

  // LayerNorm
  layernorm_k<<<dim3(Lq), blk, 0, stream>>>(pre, ln_g, ln_b, out);
}

// Round 2
// 1668.998 us; speedup vs baseline: 1.1506x; 1.1506x over previous
//
#include <hip/hip_runtime.h>
#include <hip/hip_bf16.h>
#include <math.h>

constexpr int Lq   = 2048;
constexpr int DMOD = 2048;
constexpr int NH   = 16;
constexpr int DK_  = 128;

typedef __attribute__((ext_vector_type(8))) short short8;
typedef __attribute__((ext_vector_type(4))) float f32x4;

__device__ __forceinline__ short f2bf(float f) {
  union { float f; unsigned u; } v; v.f = f;
  unsigned r = v.u + 0x7FFFu + ((v.u >> 16) & 1u);   // RTNE (inputs are finite)
  return (short)(r >> 16);
}

#define GLOAD_LDS16(g, s) \
  __builtin_amdgcn_global_load_lds((const __attribute__((address_space(1))) void*)(g), \
                                   (__attribute__((address_space(3))) void*)(s), 16, 0, 0)

// ---------------------------------------------------------------------------
// bf16 MFMA GEMM, TN: C = scale * (A @ W^T) (+bias +residual)
// A: [M x Kd] (lda), W: [N x Kd] (ldw) -- both bf16 (or A fp32 if AF32).
// Tile 128x128, BK=32, 4 waves (2x2), each wave 64x64 via 4x4 16x16x32 MFMA.
// LDS granule-XOR swizzle (free: pure lane arithmetic) keeps ds_read_b128
// fragment reads at 2-way bank aliasing instead of 8-way.
// ---------------------------------------------------------------------------
template<bool AF32, bool OUTBF>
__global__ __launch_bounds__(256)
void gemm_mfma(const void* __restrict__ Ap, const unsigned short* __restrict__ Wp,
               void* __restrict__ Cp, int Kd, int lda, int ldw, int ldc,
               long long zA, long long zW, long long zC, float scale,
               const float* __restrict__ bias, const float* __restrict__ residual,
               int ldr)
{
  __shared__ unsigned short Alds[128 * 32];   // 8 KB
  __shared__ unsigned short Blds[128 * 32];   // 8 KB
  __shared__ float eplds[4][16 * 68];         // 17 KB epilogue bounce (per-wave)

  const int tid = threadIdx.x;
  const int w   = tid >> 6;
  const int l   = tid & 63;
  const int wm  = w >> 1, wn = w & 1;
  const int m0  = blockIdx.y * 128, n0 = blockIdx.x * 128;

  const unsigned short* A_bf = (const unsigned short*)Ap + (long long)zA * blockIdx.z;
  const float*          A_f  = (const float*)Ap          + (long long)zA * blockIdx.z;
  const unsigned short* W    = Wp                        + (long long)zW * blockIdx.z;

  // staging lane map: row = chunk*16 + (l>>2), dest granule (l&3); the source
  // granule is XOR-swizzled so ds_read can de-conflict with the same XOR.
  const int srow = l >> 2;
  const int sgs  = (l & 3) ^ ((l >> 3) & 3);          // swizzled source granule
  // fragment read map: row (l&15), data granule (l>>4) -> stored granule:
  const int fgr  = (l >> 4) ^ (((l & 15) >> 1) & 3);

  f32x4 acc[4][4];
  #pragma unroll
  for (int mi = 0; mi < 4; ++mi)
    #pragma unroll
    for (int ni = 0; ni < 4; ++ni)
      acc[mi][ni] = (f32x4){0.f, 0.f, 0.f, 0.f};

  for (int kt = 0; kt < Kd; kt += 32) {
    float4 fa0, fa1, fa2, fa3;
    if constexpr (AF32) {
      const float* s0 = A_f + (size_t)(m0 + w * 32 +      srow) * lda + kt + sgs * 8;
      const float* s1 = A_f + (size_t)(m0 + w * 32 + 16 + srow) * lda + kt + sgs * 8;
      fa0 = *(const float4*)s0; fa1 = *(const float4*)(s0 + 4);
      fa2 = *(const float4*)s1; fa3 = *(const float4*)(s1 + 4);
    }
    __syncthreads();
    if constexpr (AF32) {
      short8 u0, u1;
      u0[0]=f2bf(fa0.x); u0[1]=f2bf(fa0.y); u0[2]=f2bf(fa0.z); u0[3]=f2bf(fa0.w);
      u0[4]=f2bf(fa1.x); u0[5]=f2bf(fa1.y); u0[6]=f2bf(fa1.z); u0[7]=f2bf(fa1.w);
      u1[0]=f2bf(fa2.x); u1[1]=f2bf(fa2.y); u1[2]=f2bf(fa2.z); u1[3]=f2bf(fa2.w);
      u1[4]=f2bf(fa3.x); u1[5]=f2bf(fa3.y); u1[6]=f2bf(fa3.z); u1[7]=f2bf(fa3.w);
      *(short8*)&Alds[(w * 32 +      srow) * 32 + (l & 3) * 8] = u0;
      *(short8*)&Alds[(w * 32 + 16 + srow) * 32 + (l & 3) * 8] = u1;
    } else {
      GLOAD_LDS16(A_bf + (size_t)(m0 + w * 32 +      srow) * lda + kt + sgs * 8,
                  &Alds[(w * 32) * 32]);
      GLOAD_LDS16(A_bf + (size_t)(m0 + w * 32 + 16 + srow) * lda + kt + sgs * 8,
                  &Alds[(w * 32 + 16) * 32]);
    }
    GLOAD_LDS16(W + (size_t)(n0 + w * 32 +      srow) * ldw + kt + sgs * 8,
                &Blds[(w * 32) * 32]);
    GLOAD_LDS16(W + (size_t)(n0 + w * 32 + 16 + srow) * ldw + kt + sgs * 8,
                &Blds[(w * 32 + 16) * 32]);
    __syncthreads();

    short8 af[4], bfr[4];
    #pragma unroll
    for (int mi = 0; mi < 4; ++mi)
      af[mi] = *(const short8*)&Alds[(wm * 64 + mi * 16 + (l & 15)) * 32 + fgr * 8];
    #pragma unroll
    for (int ni = 0; ni < 4; ++ni)
      bfr[ni] = *(const short8*)&Blds[(wn * 64 + ni * 16 + (l & 15)) * 32 + fgr * 8];
    #pragma unroll
    for (int mi = 0; mi < 4; ++mi)
      #pragma unroll
      for (int ni = 0; ni < 4; ++ni)
        acc[mi][ni] = __builtin_amdgcn_mfma_f32_16x16x32_bf16(af[mi], bfr[ni],
                                                              acc[mi][ni], 0, 0, 0);
  }

  // ---- epilogue: bounce each 16x64 wave-chunk through LDS for coalesced IO
  float* ep = eplds[w];
  #pragma unroll 1
  for (int mi = 0; mi < 4; ++mi) {
    __syncthreads();
    #pragma unroll
    for (int ni = 0; ni < 4; ++ni)
      #pragma unroll
      for (int r = 0; r < 4; ++r)
        ep[((l >> 4) * 4 + r) * 68 + ni * 16 + (l & 15)] = acc[mi][ni][r] * scale;
    __syncthreads();
    if constexpr (OUTBF) {
      unsigned short* C = (unsigned short*)Cp + (long long)zC * blockIdx.z;
      #pragma unroll
      for (int p = 0; p < 2; ++p) {
        const int row = p * 8 + (l >> 3), c8 = (l & 7) * 8;
        float4 v0 = *(const float4*)&ep[row * 68 + c8];
        float4 v1 = *(const float4*)&ep[row * 68 + c8 + 4];
        short8 o;
        o[0]=f2bf(v0.x); o[1]=f2bf(v0.y); o[2]=f2bf(v0.z); o[3]=f2bf(v0.w);
        o[4]=f2bf(v1.x); o[5]=f2bf(v1.y); o[6]=f2bf(v1.z); o[7]=f2bf(v1.w);
        *(short8*)&C[(size_t)(m0 + wm * 64 + mi * 16 + row) * ldc + n0 + wn * 64 + c8] = o;
      }
    } else {
      float* C = (float*)Cp + (long long)zC * blockIdx.z;
      #pragma unroll
      for (int p = 0; p < 4; ++p) {
        const int row = p * 4 + (l >> 4), c4 = (l & 15) * 4;
        float4 vv = *(const float4*)&ep[row * 68 + c4];
        const int gr = m0 + wm * 64 + mi * 16 + row;
        const int gc = n0 + wn * 64 + c4;
        if (bias) {
          const float4 bv = *(const float4*)&bias[gc];
          vv.x += bv.x; vv.y += bv.y; vv.z += bv.z; vv.w += bv.w;
        }
        if (residual) {
          const float4 rv = *(const float4*)&residual[(size_t)gr * ldr + gc];
          vv.x += rv.x; vv.y += rv.y; vv.z += rv.z; vv.w += rv.w;
        }
        *(float4*)&C[(size_t)gr * ldc + gc] = vv;
      }
    }
  }
}

// ---------------- fp32 -> bf16 bulk convert ----------------
__global__ __launch_bounds__(256)
void cvt_bf16(const float* __restrict__ s, unsigned short* __restrict__ d, int n8)
{
  const int i = blockIdx.x * 256 + threadIdx.x;
  if (i >= n8) return;
  const float4 v0 = *(const float4*)&s[i * 8];
  const float4 v1 = *(const float4*)&s[i * 8 + 4];
  short8 o;
  o[0]=f2bf(v0.x); o[1]=f2bf(v0.y); o[2]=f2bf(v0.z); o[3]=f2bf(v0.w);
  o[4]=f2bf(v1.x); o[5]=f2bf(v1.y); o[6]=f2bf(v1.z); o[7]=f2bf(v1.w);
  *(short8*)&d[i * 8] = o;
}

// ---------------- softmax + episodic mask (in place, fp32) ----------------
__global__ __launch_bounds__(256)
void softmax_mask(float* __restrict__ attn, const float* __restrict__ aw,
                  const int* __restrict__ Kp)
{
  __shared__ float red[4];
  const int row = blockIdx.x;
  const int i = row & (Lq - 1);
  float* p = attn + (long long)row * Lq;
  const int t = threadIdx.x;

  float x[8];
  float4 v0 = *(const float4*)&p[t * 8];
  float4 v1 = *(const float4*)&p[t * 8 + 4];
  x[0]=v0.x; x[1]=v0.y; x[2]=v0.z; x[3]=v0.w;
  x[4]=v1.x; x[5]=v1.y; x[6]=v1.z; x[7]=v1.w;

  float m = x[0];
  #pragma unroll
  for (int e = 1; e < 8; ++e) m = fmaxf(m, x[e]);
  #pragma unroll
  for (int off = 32; off > 0; off >>= 1) m = fmaxf(m, __shfl_down(m, off));
  const int lane = t & 63, wid = t >> 6;
  if (lane == 0) red[wid] = m;
  __syncthreads();
  m = fmaxf(fmaxf(red[0], red[1]), fmaxf(red[2], red[3]));
  __syncthreads();

  float s = 0.f;
  #pragma unroll
  for (int e = 0; e < 8; ++e) { x[e] = __expf(x[e] - m); s += x[e]; }
  #pragma unroll
  for (int off = 32; off > 0; off >>= 1) s += __shfl_down(s, off);
  if (lane == 0) red[wid] = s;
  __syncthreads();
  s = red[0] + red[1] + red[2] + red[3];
  const float inv = 1.f / s;

  const float wss = tanhf(aw[0]);
  const float wsc = tanhf(aw[1]);
  const float wdc = tanhf(aw[2]);
  const int Kv = *Kp;
  const int ci = i / Kv;

  #pragma unroll
  for (int e = 0; e < 8; ++e) {
    const int j = t * 8 + e;
    const float wgt = (j == i) ? wss : ((j / Kv == ci) ? wsc : wdc);
    x[e] *= inv * wgt;
  }
  v0.x=x[0]; v0.y=x[1]; v0.z=x[2]; v0.w=x[3];
  v1.x=x[4]; v1.y=x[5]; v1.z=x[6]; v1.w=x[7];
  *(float4*)&p[t * 8]     = v0;
  *(float4*)&p[t * 8 + 4] = v1;
}

// ---------------- rowwise LayerNorm ----------------
__global__ __launch_bounds__(256)
void layernorm_k(const float* __restrict__ X, const float* __restrict__ gg,
                 const float* __restrict__ bb, float* __restrict__ O)
{
  __shared__ float redA[4], redB[4];
  const int row = blockIdx.x;
  const int t = threadIdx.x;
  const float* p = X + (long long)row * DMOD;

  float x[8];
  float4 v0 = *(const float4*)&p[t * 8];
  float4 v1 = *(const float4*)&p[t * 8 + 4];
  x[0]=v0.x; x[1]=v0.y; x[2]=v0.z; x[3]=v0.w;
  x[4]=v1.x; x[5]=v1.y; x[6]=v1.z; x[7]=v1.w;

  float s = 0.f, s2 = 0.f;
  #pragma unroll
  for (int e = 0; e < 8; ++e) { s += x[e]; s2 += x[e] * x[e]; }
  #pragma unroll
  for (int off = 32; off > 0; off >>= 1) {
    s  += __shfl_down(s, off);
    s2 += __shfl_down(s2, off);
  }
  const int lane = t & 63, wid = t >> 6;
  if (lane == 0) { redA[wid] = s; redB[wid] = s2; }
  __syncthreads();
  s  = redA[0] + redA[1] + redA[2] + redA[3];
  s2 = redB[0] + redB[1] + redB[2] + redB[3];

  const float mu  = s * (1.f / (float)DMOD);
  const float var = s2 * (1.f / (float)DMOD) - mu * mu;
  const float rs  = rsqrtf(var + 1e-5f);

  float y[8];
  #pragma unroll
  for (int e = 0; e < 8; ++e) {
    const int j = t * 8 + e;
    y[e] = (x[e] - mu) * rs * gg[j] + bb[j];
  }
  v0.x=y[0]; v0.y=y[1]; v0.z=y[2]; v0.w=y[3];
  v1.x=y[4]; v1.y=y[5]; v1.z=y[6]; v1.w=y[7];
  float* o = O + (long long)row * DMOD;
  *(float4*)&o[t * 8]     = v0;
  *(float4*)&o[t * 8 + 4] = v1;
}

extern "C" void kernel_launch(void* const* d_in, const int* in_sizes, int n_in,
                              void* d_out, int out_size, void* d_ws, size_t ws_size,
                              hipStream_t stream)
{
  const float* q    = (const float*)d_in[0];
  const float* k    = (const float*)d_in[1];
  const float* v    = (const float*)d_in[2];
  const float* w_qs = (const float*)d_in[3];
  const float* w_ks = (const float*)d_in[4];
  const float* w_vs = (const float*)d_in[5];
  const float* aw   = (const float*)d_in[6];
  const float* fc_w = (const float*)d_in[7];
  const float* fc_b = (const float*)d_in[8];
  const float* ln_g = (const float*)d_in[9];
  const float* ln_b = (const float*)d_in[10];
  const int*   Kp   = (const int*)d_in[12];

  float* out  = (float*)d_out;
  float* attn = out + (size_t)Lq * DMOD;             // S / masked attn, fp32

  const size_t SLOT = 8ull * 1024 * 1024;            // 4M bf16 = 8 MB
  char* ws = (char*)d_ws;
  unsigned short* q_bf   = (unsigned short*)(ws + 0 * SLOT);
  unsigned short* k_bf   = (unsigned short*)(ws + 1 * SLOT);
  unsigned short* v_bf   = (unsigned short*)(ws + 2 * SLOT);
  unsigned short* wq_bf  = (unsigned short*)(ws + 3 * SLOT);
  unsigned short* wk_bf  = (unsigned short*)(ws + 4 * SLOT);
  unsigned short* wv_bf  = (unsigned short*)(ws + 5 * SLOT);
  unsigned short* qh_bf  = (unsigned short*)(ws + 6 * SLOT);
  unsigned short* kh_bf  = q_bf;                     // reuse after proj-Q
  unsigned short* vhT_bf = k_bf;                     // reuse after proj-K
  unsigned short* fcw_bf = v_bf;                     // reuse after proj-V
  unsigned short* oc_bf  = wq_bf;                    // reuse after proj-Q
  float*          pre    = (float*)(ws + 4 * SLOT);  // 16 MB, after wk/wv dead

  const dim3 blk(256);
  const int N8 = (DMOD * DMOD) / 8;                  // 524288
  const float qk_scale = 1.0f / sqrtf((float)DK_);

  cvt_bf16<<<dim3(N8 / 256), blk, 0, stream>>>(q,    q_bf,  N8);
  cvt_bf16<<<dim3(N8 / 256), blk, 0, stream>>>(k,    k_bf,  N8);
  cvt_bf16<<<dim3(N8 / 256), blk, 0, stream>>>(v,    v_bf,  N8);
  cvt_bf16<<<dim3(N8 / 256), blk, 0, stream>>>(w_qs, wq_bf, N8);
  cvt_bf16<<<dim3(N8 / 256), blk, 0, stream>>>(w_ks, wk_bf, N8);
  cvt_bf16<<<dim3(N8 / 256), blk, 0, stream>>>(w_vs, wv_bf, N8);

  // qh = q @ w_qs^T ; kh = k @ w_ks^T     (bf16 out, [Lq][2048])
  gemm_mfma<false,true><<<dim3(16,16,1), blk, 0, stream>>>(
      q_bf, wq_bf, qh_bf, DMOD, DMOD, DMOD, DMOD, 0, 0, 0, 1.f, nullptr, nullptr, 0);
  gemm_mfma<false,true><<<dim3(16,16,1), blk, 0, stream>>>(
      k_bf, wk_bf, kh_bf, DMOD, DMOD, DMOD, DMOD, 0, 0, 0, 1.f, nullptr, nullptr, 0);
  // vh^T = w_vs @ v^T = TN(w_vs, v)       (bf16 out, [2048][Lq], pre-transposed)
  gemm_mfma<false,true><<<dim3(16,16,1), blk, 0, stream>>>(
      wv_bf, v_bf, vhT_bf, DMOD, DMOD, DMOD, Lq, 0, 0, 0, 1.f, nullptr, nullptr, 0);

  // S_h = qh_h @ kh_h^T / sqrt(dk)        (fp32 out into d_out attn region)
  gemm_mfma<false,false><<<dim3(16,16,NH), blk, 0, stream>>>(
      qh_bf, kh_bf, attn, DK_, DMOD, DMOD, Lq,
      128, 128, (long long)Lq * Lq, qk_scale, nullptr, nullptr, 0);

  // softmax + mask, in place on d_out attn
  softmax_mask<<<dim3(NH * Lq), blk, 0, stream>>>(attn, aw, Kp);

  cvt_bf16<<<dim3(N8 / 256), blk, 0, stream>>>(fc_w, fcw_bf, N8);

  // O_h = attn_h @ vh_h = TN(attn_h fp32 -> bf16 staged, vhT rows h*128..)
  gemm_mfma<true,true><<<dim3(1,16,NH), blk, 0, stream>>>(
      attn, vhT_bf, oc_bf, Lq, Lq, Lq, DMOD,
      (long long)Lq * Lq, (long long)128 * Lq, 128, 1.f, nullptr, nullptr, 0);

  // pre = oc @ fc_w^T + fc_b + q          (fp32 out)
  gemm_mfma<false,false><<<dim3(16,16,1), blk, 0, stream>>>(
      oc_bf, fcw_bf, pre, DMOD, DMOD, DMOD, DMOD,
      0, 0, 0, 1.f, fc_b, q, DMOD);

  layernorm_k<<<dim3(Lq), blk, 0, stream>>>(pre, ln_g, ln_b, out);
}

// Round 3
// 817.090 us; speedup vs baseline: 2.3503x; 2.0426x over previous
//
#include <hip/hip_runtime.h>
#include <hip/hip_bf16.h>
#include <math.h>

constexpr int Lq   = 2048;
constexpr int DMOD = 2048;
constexpr int NH   = 16;
constexpr int DK_  = 128;

typedef __attribute__((ext_vector_type(8))) short short8;
typedef __attribute__((ext_vector_type(4))) float f32x4;

__device__ __forceinline__ short f2bf(float f) {
  union { float f; unsigned u; } v; v.f = f;
  unsigned r = v.u + 0x7FFFu + ((v.u >> 16) & 1u);   // RTNE (inputs are finite)
  return (short)(r >> 16);
}

#define GLOAD_LDS16(g, s) \
  __builtin_amdgcn_global_load_lds((const __attribute__((address_space(1))) void*)(g), \
                                   (__attribute__((address_space(3))) void*)(s), 16, 0, 0)

// ---------------------------------------------------------------------------
// bf16 MFMA GEMM, TN: C = scale * (A @ W^T) (+bias +residual)
// A: [M x Kd] (lda), W: [N x Kd] (ldw) -- both bf16 (or A fp32 if AF32).
// Tile 128x128, BK=32, 4 waves (2x2), each wave 64x64 via 4x4 16x16x32 MFMA.
// NOTE: epilogue mi-loop MUST be fully unrolled -- a runtime index into
// acc[][] sends the whole accumulator array to scratch (rule #20; round-2
// counters showed 1.5 GB/dispatch of scratch write traffic, VGPR=64).
// ---------------------------------------------------------------------------
template<bool AF32, bool OUTBF>
__global__ __launch_bounds__(256)
void gemm_mfma(const void* __restrict__ Ap, const unsigned short* __restrict__ Wp,
               void* __restrict__ Cp, int Kd, int lda, int ldw, int ldc,
               long long zA, long long zW, long long zC, float scale,
               const float* __restrict__ bias, const float* __restrict__ residual,
               int ldr)
{
  __shared__ unsigned short Alds[128 * 32];   // 8 KB
  __shared__ unsigned short Blds[128 * 32];   // 8 KB
  __shared__ float eplds[4][16 * 68];         // 17 KB epilogue bounce (per-wave)

  const int tid = threadIdx.x;
  const int w   = tid >> 6;
  const int l   = tid & 63;
  const int wm  = w >> 1, wn = w & 1;
  const int m0  = blockIdx.y * 128, n0 = blockIdx.x * 128;

  const unsigned short* A_bf = (const unsigned short*)Ap + (long long)zA * blockIdx.z;
  const float*          A_f  = (const float*)Ap          + (long long)zA * blockIdx.z;
  const unsigned short* W    = Wp                        + (long long)zW * blockIdx.z;

  // staging lane map: row = chunk*16 + (l>>2), dest granule (l&3); the source
  // granule is XOR-swizzled so ds_read can de-conflict with the same XOR.
  const int srow = l >> 2;
  const int sgs  = (l & 3) ^ ((l >> 3) & 3);          // swizzled source granule
  // fragment read map: row (l&15), data granule (l>>4) -> stored granule:
  const int fgr  = (l >> 4) ^ (((l & 15) >> 1) & 3);

  f32x4 acc[4][4];
  #pragma unroll
  for (int mi = 0; mi < 4; ++mi)
    #pragma unroll
    for (int ni = 0; ni < 4; ++ni)
      acc[mi][ni] = (f32x4){0.f, 0.f, 0.f, 0.f};

  for (int kt = 0; kt < Kd; kt += 32) {
    float4 fa0, fa1, fa2, fa3;
    if constexpr (AF32) {
      const float* s0 = A_f + (size_t)(m0 + w * 32 +      srow) * lda + kt + sgs * 8;
      const float* s1 = A_f + (size_t)(m0 + w * 32 + 16 + srow) * lda + kt + sgs * 8;
      fa0 = *(const float4*)s0; fa1 = *(const float4*)(s0 + 4);
      fa2 = *(const float4*)s1; fa3 = *(const float4*)(s1 + 4);
    }
    __syncthreads();
    if constexpr (AF32) {
      short8 u0, u1;
      u0[0]=f2bf(fa0.x); u0[1]=f2bf(fa0.y); u0[2]=f2bf(fa0.z); u0[3]=f2bf(fa0.w);
      u0[4]=f2bf(fa1.x); u0[5]=f2bf(fa1.y); u0[6]=f2bf(fa1.z); u0[7]=f2bf(fa1.w);
      u1[0]=f2bf(fa2.x); u1[1]=f2bf(fa2.y); u1[2]=f2bf(fa2.z); u1[3]=f2bf(fa2.w);
      u1[4]=f2bf(fa3.x); u1[5]=f2bf(fa3.y); u1[6]=f2bf(fa3.z); u1[7]=f2bf(fa3.w);
      *(short8*)&Alds[(w * 32 +      srow) * 32 + (l & 3) * 8] = u0;
      *(short8*)&Alds[(w * 32 + 16 + srow) * 32 + (l & 3) * 8] = u1;
    } else {
      GLOAD_LDS16(A_bf + (size_t)(m0 + w * 32 +      srow) * lda + kt + sgs * 8,
                  &Alds[(w * 32) * 32]);
      GLOAD_LDS16(A_bf + (size_t)(m0 + w * 32 + 16 + srow) * lda + kt + sgs * 8,
                  &Alds[(w * 32 + 16) * 32]);
    }
    GLOAD_LDS16(W + (size_t)(n0 + w * 32 +      srow) * ldw + kt + sgs * 8,
                &Blds[(w * 32) * 32]);
    GLOAD_LDS16(W + (size_t)(n0 + w * 32 + 16 + srow) * ldw + kt + sgs * 8,
                &Blds[(w * 32 + 16) * 32]);
    __syncthreads();

    short8 af[4], bfr[4];
    #pragma unroll
    for (int mi = 0; mi < 4; ++mi)
      af[mi] = *(const short8*)&Alds[(wm * 64 + mi * 16 + (l & 15)) * 32 + fgr * 8];
    #pragma unroll
    for (int ni = 0; ni < 4; ++ni)
      bfr[ni] = *(const short8*)&Blds[(wn * 64 + ni * 16 + (l & 15)) * 32 + fgr * 8];
    #pragma unroll
    for (int mi = 0; mi < 4; ++mi)
      #pragma unroll
      for (int ni = 0; ni < 4; ++ni)
        acc[mi][ni] = __builtin_amdgcn_mfma_f32_16x16x32_bf16(af[mi], bfr[ni],
                                                              acc[mi][ni], 0, 0, 0);
  }

  // ---- epilogue: bounce each 16x64 wave-chunk through LDS for coalesced IO
  // FULLY UNROLLED so every acc index is compile-time constant (rule #20).
  float* ep = eplds[w];
  #pragma unroll
  for (int mi = 0; mi < 4; ++mi) {
    __syncthreads();
    #pragma unroll
    for (int ni = 0; ni < 4; ++ni)
      #pragma unroll
      for (int r = 0; r < 4; ++r)
        ep[((l >> 4) * 4 + r) * 68 + ni * 16 + (l & 15)] = acc[mi][ni][r] * scale;
    __syncthreads();
    if constexpr (OUTBF) {
      unsigned short* C = (unsigned short*)Cp + (long long)zC * blockIdx.z;
      #pragma unroll
      for (int p = 0; p < 2; ++p) {
        const int row = p * 8 + (l >> 3), c8 = (l & 7) * 8;
        float4 v0 = *(const float4*)&ep[row * 68 + c8];
        float4 v1 = *(const float4*)&ep[row * 68 + c8 + 4];
        short8 o;
        o[0]=f2bf(v0.x); o[1]=f2bf(v0.y); o[2]=f2bf(v0.z); o[3]=f2bf(v0.w);
        o[4]=f2bf(v1.x); o[5]=f2bf(v1.y); o[6]=f2bf(v1.z); o[7]=f2bf(v1.w);
        *(short8*)&C[(size_t)(m0 + wm * 64 + mi * 16 + row) * ldc + n0 + wn * 64 + c8] = o;
      }
    } else {
      float* C = (float*)Cp + (long long)zC * blockIdx.z;
      #pragma unroll
      for (int p = 0; p < 4; ++p) {
        const int row = p * 4 + (l >> 4), c4 = (l & 15) * 4;
        float4 vv = *(const float4*)&ep[row * 68 + c4];
        const int gr = m0 + wm * 64 + mi * 16 + row;
        const int gc = n0 + wn * 64 + c4;
        if (bias) {
          const float4 bv = *(const float4*)&bias[gc];
          vv.x += bv.x; vv.y += bv.y; vv.z += bv.z; vv.w += bv.w;
        }
        if (residual) {
          const float4 rv = *(const float4*)&residual[(size_t)gr * ldr + gc];
          vv.x += rv.x; vv.y += rv.y; vv.z += rv.z; vv.w += rv.w;
        }
        *(float4*)&C[(size_t)gr * ldc + gc] = vv;
      }
    }
  }
}

// ---------------- fp32 -> bf16 bulk convert ----------------
__global__ __launch_bounds__(256)
void cvt_bf16(const float* __restrict__ s, unsigned short* __restrict__ d, int n8)
{
  const int i = blockIdx.x * 256 + threadIdx.x;
  if (i >= n8) return;
  const float4 v0 = *(const float4*)&s[i * 8];
  const float4 v1 = *(const float4*)&s[i * 8 + 4];
  short8 o;
  o[0]=f2bf(v0.x); o[1]=f2bf(v0.y); o[2]=f2bf(v0.z); o[3]=f2bf(v0.w);
  o[4]=f2bf(v1.x); o[5]=f2bf(v1.y); o[6]=f2bf(v1.z); o[7]=f2bf(v1.w);
  *(short8*)&d[i * 8] = o;
}

// ---------------- softmax + episodic mask (in place, fp32) ----------------
__global__ __launch_bounds__(256)
void softmax_mask(float* __restrict__ attn, const float* __restrict__ aw,
                  const int* __restrict__ Kp)
{
  __shared__ float red[4];
  const int row = blockIdx.x;
  const int i = row & (Lq - 1);
  float* p = attn + (long long)row * Lq;
  const int t = threadIdx.x;

  float x[8];
  float4 v0 = *(const float4*)&p[t * 8];
  float4 v1 = *(const float4*)&p[t * 8 + 4];
  x[0]=v0.x; x[1]=v0.y; x[2]=v0.z; x[3]=v0.w;
  x[4]=v1.x; x[5]=v1.y; x[6]=v1.z; x[7]=v1.w;

  float m = x[0];
  #pragma unroll
  for (int e = 1; e < 8; ++e) m = fmaxf(m, x[e]);
  #pragma unroll
  for (int off = 32; off > 0; off >>= 1) m = fmaxf(m, __shfl_down(m, off));
  const int lane = t & 63, wid = t >> 6;
  if (lane == 0) red[wid] = m;
  __syncthreads();
  m = fmaxf(fmaxf(red[0], red[1]), fmaxf(red[2], red[3]));
  __syncthreads();

  float s = 0.f;
  #pragma unroll
  for (int e = 0; e < 8; ++e) { x[e] = __expf(x[e] - m); s += x[e]; }
  #pragma unroll
  for (int off = 32; off > 0; off >>= 1) s += __shfl_down(s, off);
  if (lane == 0) red[wid] = s;
  __syncthreads();
  s = red[0] + red[1] + red[2] + red[3];
  const float inv = 1.f / s;

  const float wss = tanhf(aw[0]);
  const float wsc = tanhf(aw[1]);
  const float wdc = tanhf(aw[2]);
  const int Kv = *Kp;
  const int ci = i / Kv;

  #pragma unroll
  for (int e = 0; e < 8; ++e) {
    const int j = t * 8 + e;
    const float wgt = (j == i) ? wss : ((j / Kv == ci) ? wsc : wdc);
    x[e] *= inv * wgt;
  }
  v0.x=x[0]; v0.y=x[1]; v0.z=x[2]; v0.w=x[3];
  v1.x=x[4]; v1.y=x[5]; v1.z=x[6]; v1.w=x[7];
  *(float4*)&p[t * 8]     = v0;
  *(float4*)&p[t * 8 + 4] = v1;
}

// ---------------- rowwise LayerNorm ----------------
__global__ __launch_bounds__(256)
void layernorm_k(const float* __restrict__ X, const float* __restrict__ gg,
                 const float* __restrict__ bb, float* __restrict__ O)
{
  __shared__ float redA[4], redB[4];
  const int row = blockIdx.x;
  const int t = threadIdx.x;
  const float* p = X + (long long)row * DMOD;

  float x[8];
  float4 v0 = *(const float4*)&p[t * 8];
  float4 v1 = *(const float4*)&p[t * 8 + 4];
  x[0]=v0.x; x[1]=v0.y; x[2]=v0.z; x[3]=v0.w;
  x[4]=v1.x; x[5]=v1.y; x[6]=v1.z; x[7]=v1.w;

  float s = 0.f, s2 = 0.f;
  #pragma unroll
  for (int e = 0; e < 8; ++e) { s += x[e]; s2 += x[e] * x[e]; }
  #pragma unroll
  for (int off = 32; off > 0; off >>= 1) {
    s  += __shfl_down(s, off);
    s2 += __shfl_down(s2, off);
  }
  const int lane = t & 63, wid = t >> 6;
  if (lane == 0) { redA[wid] = s; redB[wid] = s2; }
  __syncthreads();
  s  = redA[0] + redA[1] + redA[2] + redA[3];
  s2 = redB[0] + redB[1] + redB[2] + redB[3];

  const float mu  = s * (1.f / (float)DMOD);
  const float var = s2 * (1.f / (float)DMOD) - mu * mu;
  const float rs  = rsqrtf(var + 1e-5f);

  float y[8];
  #pragma unroll
  for (int e = 0; e < 8; ++e) {
    const int j = t * 8 + e;
    y[e] = (x[e] - mu) * rs * gg[j] + bb[j];
  }
  v0.x=y[0]; v0.y=y[1]; v0.z=y[2]; v0.w=y[3];
  v1.x=y[4]; v1.y=y[5]; v1.z=y[6]; v1.w=y[7];
  float* o = O + (long long)row * DMOD;
  *(float4*)&o[t * 8]     = v0;
  *(float4*)&o[t * 8 + 4] = v1;
}

extern "C" void kernel_launch(void* const* d_in, const int* in_sizes, int n_in,
                              void* d_out, int out_size, void* d_ws, size_t ws_size,
                              hipStream_t stream)
{
  const float* q    = (const float*)d_in[0];
  const float* k    = (const float*)d_in[1];
  const float* v    = (const float*)d_in[2];
  const float* w_qs = (const float*)d_in[3];
  const float* w_ks = (const float*)d_in[4];
  const float* w_vs = (const float*)d_in[5];
  const float* aw   = (const float*)d_in[6];
  const float* fc_w = (const float*)d_in[7];
  const float* fc_b = (const float*)d_in[8];
  const float* ln_g = (const float*)d_in[9];
  const float* ln_b = (const float*)d_in[10];
  const int*   Kp   = (const int*)d_in[12];

  float* out  = (float*)d_out;
  float* attn = out + (size_t)Lq * DMOD;             // S / masked attn, fp32

  const size_t SLOT = 8ull * 1024 * 1024;            // 4M bf16 = 8 MB
  char* ws = (char*)d_ws;
  unsigned short* q_bf   = (unsigned short*)(ws + 0 * SLOT);
  unsigned short* k_bf   = (unsigned short*)(ws + 1 * SLOT);
  unsigned short* v_bf   = (unsigned short*)(ws + 2 * SLOT);
  unsigned short* wq_bf  = (unsigned short*)(ws + 3 * SLOT);
  unsigned short* wk_bf  = (unsigned short*)(ws + 4 * SLOT);
  unsigned short* wv_bf  = (unsigned short*)(ws + 5 * SLOT);
  unsigned short* qh_bf  = (unsigned short*)(ws + 6 * SLOT);
  unsigned short* kh_bf  = q_bf;                     // reuse after proj-Q
  unsigned short* vhT_bf = k_bf;                     // reuse after proj-K
  unsigned short* fcw_bf = v_bf;                     // reuse after proj-V
  unsigned short* oc_bf  = wq_bf;                    // reuse after proj-Q
  float*          pre    = (float*)(ws + 4 * SLOT);  // 16 MB, after wk/wv dead

  const dim3 blk(256);
  const int N8 = (DMOD * DMOD) / 8;                  // 524288
  const float qk_scale = 1.0f / sqrtf((float)DK_);

  cvt_bf16<<<dim3(N8 / 256), blk, 0, stream>>>(q,    q_bf,  N8);
  cvt_bf16<<<dim3(N8 / 256), blk, 0, stream>>>(k,    k_bf,  N8);
  cvt_bf16<<<dim3(N8 / 256), blk, 0, stream>>>(v,    v_bf,  N8);
  cvt_bf16<<<dim3(N8 / 256), blk, 0, stream>>>(w_qs, wq_bf, N8);
  cvt_bf16<<<dim3(N8 / 256), blk, 0, stream>>>(w_ks, wk_bf, N8);
  cvt_bf16<<<dim3(N8 / 256), blk, 0, stream>>>(w_vs, wv_bf, N8);

  // qh = q @ w_qs^T ; kh = k @ w_ks^T     (bf16 out, [Lq][2048])
  gemm_mfma<false,true><<<dim3(16,16,1), blk, 0, stream>>>(
      q_bf, wq_bf, qh_bf, DMOD, DMOD, DMOD, DMOD, 0, 0, 0, 1.f, nullptr, nullptr, 0);
  gemm_mfma<false,true><<<dim3(16,16,1), blk, 0, stream>>>(
      k_bf, wk_bf, kh_bf, DMOD, DMOD, DMOD, DMOD, 0, 0, 0, 1.f, nullptr, nullptr, 0);
  // vh^T = w_vs @ v^T = TN(w_vs, v)       (bf16 out, [2048][Lq], pre-transposed)
  gemm_mfma<false,true><<<dim3(16,16,1), blk, 0, stream>>>(
      wv_bf, v_bf, vhT_bf, DMOD, DMOD, DMOD, Lq, 0, 0, 0, 1.f, nullptr, nullptr, 0);

  // S_h = qh_h @ kh_h^T / sqrt(dk)        (fp32 out into d_out attn region)
  gemm_mfma<false,false><<<dim3(16,16,NH), blk, 0, stream>>>(
      qh_bf, kh_bf, attn, DK_, DMOD, DMOD, Lq,
      128, 128, (long long)Lq * Lq, qk_scale, nullptr, nullptr, 0);

  // softmax + mask, in place on d_out attn
  softmax_mask<<<dim3(NH * Lq), blk, 0, stream>>>(attn, aw, Kp);

  cvt_bf16<<<dim3(N8 / 256), blk, 0, stream>>>(fc_w, fcw_bf, N8);

  // O_h = attn_h @ vh_h = TN(attn_h fp32 -> bf16 staged, vhT rows h*128..)
  gemm_mfma<true,true><<<dim3(1,16,NH), blk, 0, stream>>>(
      attn, vhT_bf, oc_bf, Lq, Lq, Lq, DMOD,
      (long long)Lq * Lq, (long long)128 * Lq, 128, 1.f, nullptr, nullptr, 0);

  // pre = oc @ fc_w^T + fc_b + q          (fp32 out)
  gemm_mfma<false,false><<<dim3(16,16,1), blk, 0, stream>>>(
      oc_bf, fcw_bf, pre, DMOD, DMOD, DMOD, DMOD,
      0, 0, 0, 1.f, fc_b, q, DMOD);

  layernorm_k<<<dim3(Lq), blk, 0, stream>>>(pre, ln_g, ln_b, out);
}